// Round 2
// baseline (1882.918 us; speedup 1.0000x reference)
//
#include <hip/hip_runtime.h>
#include <math.h>

#define B_ 64
#define T_ 2048
#define D_ 256
#define H_ 128

// -------------------------------------------------------------------------
// helpers
// -------------------------------------------------------------------------
__device__ __forceinline__ float rlane(float v, int l) {
    return __int_as_float(__builtin_amdgcn_readlane(__float_as_int(v), l));
}
__device__ __forceinline__ float hard_sig(float x) {
    return fminf(fmaxf(fmaf(x, 0.2f, 0.5f), 0.0f), 1.0f);
}
__device__ __forceinline__ float fast_tanh(float x) {
    float ax = fabsf(x);
    float e  = __expf(-2.0f * ax);
    float r  = (1.0f - e) / (1.0f + e);
    return copysignf(r, x);
}
__device__ __forceinline__ float softplus_f(float x) {
    float ax = fabsf(x);
    return fmaxf(x, 0.0f) + __logf(1.0f + __expf(-ax));
}

// -------------------------------------------------------------------------
// Projection: xx[b,tt,j] = X[b,t0+tt,:] @ W[:,j] + b[j]
//             xg[b,tt,j] = X[b,t0+tt,:] @ Wg[:,j] + bg[j]
// 256 threads: tx = tid&31 -> cols 4*tx..4*tx+3 ; ty = tid>>5 -> rows ty*8..+7
// 64 rows per block. No LDS: X rows broadcast across tx (same-address lanes
// coalesce to one L1 transaction), W rows coalesced across tx and L2-hot.
// -------------------------------------------------------------------------
__global__ __launch_bounds__(256) void proj_kernel(
    const float* __restrict__ X, const float* __restrict__ W,
    const float* __restrict__ Wg, const float* __restrict__ bias,
    const float* __restrict__ biasg, float* __restrict__ xxw,
    float* __restrict__ xgw, int t0, int Tc)
{
    const int tid = threadIdx.x;
    const int tx  = tid & 31;
    const int ty  = tid >> 5;
    const long rowbase = (long)blockIdx.x * 64;     // chunk-local row (b*Tc + tt)
    const int  b      = (int)(rowbase / Tc);        // Tc % 64 == 0 -> same b for whole block
    const int  ttbase = (int)(rowbase % Tc);
    const float* xbase = X + ((long)b * T_ + t0 + ttbase) * D_;

    float accx[8][4];
    float accg[8][4];
#pragma unroll
    for (int r = 0; r < 8; ++r)
#pragma unroll
        for (int c = 0; c < 4; ++c) { accx[r][c] = 0.f; accg[r][c] = 0.f; }

    for (int k = 0; k < D_; k += 4) {
        float wA[4][4], wG[4][4];
#pragma unroll
        for (int kk = 0; kk < 4; ++kk) {
            float4 tw = *(const float4*)&W [(long)(k + kk) * H_ + tx * 4];
            float4 tg = *(const float4*)&Wg[(long)(k + kk) * H_ + tx * 4];
            wA[kk][0] = tw.x; wA[kk][1] = tw.y; wA[kk][2] = tw.z; wA[kk][3] = tw.w;
            wG[kk][0] = tg.x; wG[kk][1] = tg.y; wG[kk][2] = tg.z; wG[kk][3] = tg.w;
        }
#pragma unroll
        for (int r = 0; r < 8; ++r) {
            float4 xv = *(const float4*)&xbase[(long)(ty * 8 + r) * D_ + k];
            float xr[4] = {xv.x, xv.y, xv.z, xv.w};
#pragma unroll
            for (int c = 0; c < 4; ++c)
#pragma unroll
                for (int kk = 0; kk < 4; ++kk) {
                    accx[r][c] = fmaf(xr[kk], wA[kk][c], accx[r][c]);
                    accg[r][c] = fmaf(xr[kk], wG[kk][c], accg[r][c]);
                }
        }
    }

    float4 bj  = *(const float4*)&bias [tx * 4];
    float4 bgj = *(const float4*)&biasg[tx * 4];
#pragma unroll
    for (int r = 0; r < 8; ++r) {
        long row = rowbase + ty * 8 + r;
        float4 ox, og;
        ox.x = accx[r][0] + bj.x;  ox.y = accx[r][1] + bj.y;
        ox.z = accx[r][2] + bj.z;  ox.w = accx[r][3] + bj.w;
        og.x = accg[r][0] + bgj.x; og.y = accg[r][1] + bgj.y;
        og.z = accg[r][2] + bgj.z; og.w = accg[r][3] + bgj.w;
        *(float4*)&xxw[row * H_ + tx * 4] = ox;
        *(float4*)&xgw[row * H_ + tx * 4] = og;
    }
}

// -------------------------------------------------------------------------
// Scan: one block per batch chain. 512 threads: j = tid&127 (output col),
// q = tid>>7 in 0..3 (reduction slice of 32 i's). U columns live in VGPRs
// (U re-read from LDS every step would be LDS-BW-bound). h broadcast via
// v_readlane (SGPR path) from a per-wave "bank" register.
// -------------------------------------------------------------------------
__global__ __launch_bounds__(512) void scan_kernel(
    const float* __restrict__ xxw, const float* __restrict__ xgw,
    const float* __restrict__ U, const float* __restrict__ Ug,
    float* __restrict__ hstate, float* __restrict__ hout,
    int t0, int Tc)
{
    const int tid    = threadIdx.x;
    const int j      = tid & 127;
    const int q      = tid >> 7;         // group-uniform (2 waves per group)
    const int lane31 = tid & 31;
    const int i0     = q * 32;
    const int b      = blockIdx.x;

    __shared__ float hl[128];
    __shared__ float zp_l[4][128];
    __shared__ float gp_l[4][128];

    // U fragments in registers: Ureg[i] = U[(i0+i)][j]
    float Ureg[32], Ugreg[32];
#pragma unroll
    for (int i = 0; i < 32; ++i) {
        Ureg[i]  = U [(long)(i0 + i) * H_ + j];
        Ugreg[i] = Ug[(long)(i0 + i) * H_ + j];
    }

    const float* xxb = xxw + (long)b * Tc * H_;
    const float* xgb = xgw + (long)b * Tc * H_;

    float h0 = (t0 == 0) ? 0.0f : hstate[b * H_ + j];
    float hcur = h0;
    if (q == 0) hl[j] = h0;
    __syncthreads();

    // per-wave banks: lanes 0..31 hold slice values (duplicated in 32..63)
    float hbank  = hl[i0 + lane31];
    float xgbank = xgb[(long)0 * H_ + i0 + lane31];
    float abank  = xgbank * hbank;       // a_t = xg_t * h_{t-1}

    float xx_cur = xxb[j];
    int   t1     = (1 < Tc) ? 1 : Tc - 1;
    float xx_nxt = xxb[(long)t1 * H_ + j];
    float xgbank_nxt = xgb[(long)t1 * H_ + i0 + lane31];

    for (int t = 0; t < Tc; ++t) {
        // ---- matvec partials over this group's 32-i slice ----
        float zp0 = 0.f, zp1 = 0.f, gp0 = 0.f, gp1 = 0.f;
#pragma unroll
        for (int i = 0; i < 32; i += 2) {
            float hs0 = rlane(hbank, i);
            float as0 = rlane(abank, i);
            float hs1 = rlane(hbank, i + 1);
            float as1 = rlane(abank, i + 1);
            zp0 = fmaf(hs0, Ureg[i],     zp0);
            gp0 = fmaf(as0, Ugreg[i],    gp0);
            zp1 = fmaf(hs1, Ureg[i + 1], zp1);
            gp1 = fmaf(as1, Ugreg[i + 1], gp1);
        }
        zp_l[q][j] = zp0 + zp1;
        gp_l[q][j] = gp0 + gp1;
        __syncthreads();

        // ---- epilogue (groups 0-1 compute; q==0 publishes) ----
        if (tid < 256) {
            float zsum = xx_cur + zp_l[0][j] + zp_l[1][j] + zp_l[2][j] + zp_l[3][j];
            float gsum = gp_l[0][j] + gp_l[1][j] + gp_l[2][j] + gp_l[3][j];
            float z    = hard_sig(zsum);
            float zg   = fast_tanh(gsum);
            float zo   = softplus_f(hcur * zg);
            float hnew = fmaf(z, zo - hcur, hcur);   // z*zo + (1-z)*hcur
            if (q == 0) hl[j] = hnew;
            hcur = hnew;
        }
        __syncthreads();

        // ---- refresh banks / prefetch for next step ----
        hbank  = hl[i0 + lane31];
        abank  = xgbank_nxt * hbank;     // a_{t+1} = xg_{t+1} * h_t
        xx_cur = xx_nxt;
        int t2 = (t + 2 < Tc) ? t + 2 : Tc - 1;
        xx_nxt     = xxb[(long)t2 * H_ + j];
        xgbank_nxt = xgb[(long)t2 * H_ + i0 + lane31];
    }

    if (q == 0) hout[b * H_ + j] = hcur;
}

// -------------------------------------------------------------------------
// launch
// -------------------------------------------------------------------------
extern "C" void kernel_launch(void* const* d_in, const int* in_sizes, int n_in,
                              void* d_out, int out_size, void* d_ws, size_t ws_size,
                              hipStream_t stream)
{
    const float* X  = (const float*)d_in[0];
    const float* W  = (const float*)d_in[1];
    const float* U  = (const float*)d_in[2];
    const float* bb = (const float*)d_in[3];
    const float* Wg = (const float*)d_in[4];
    const float* bg = (const float*)d_in[5];
    const float* Ug = (const float*)d_in[6];
    float* out = (float*)d_out;

    // choose largest chunk of T whose staging fits in ws (deterministic per launch)
    int Tc = 64;
    const int cands[6] = {2048, 1024, 512, 256, 128, 64};
    for (int ci = 0; ci < 6; ++ci) {
        size_t need = (size_t)2 * B_ * cands[ci] * H_ * sizeof(float)
                    + (size_t)B_ * H_ * sizeof(float);
        if (ws_size >= need) { Tc = cands[ci]; break; }
    }

    float* xxw = (float*)d_ws;
    float* xgw = xxw + (size_t)B_ * Tc * H_;
    float* hst = xgw + (size_t)B_ * Tc * H_;

    for (int t0 = 0; t0 < T_; t0 += Tc) {
        proj_kernel<<<B_ * Tc / 64, 256, 0, stream>>>(X, W, Wg, bb, bg, xxw, xgw, t0, Tc);
        float* ho = (t0 + Tc >= T_) ? out : hst;
        scan_kernel<<<B_, 512, 0, stream>>>(xxw, xgw, U, Ug, hst, ho, t0, Tc);
    }
}

// Round 4
// 1788.186 us; speedup vs baseline: 1.0530x; 1.0530x over previous
//
#include <hip/hip_runtime.h>
#include <math.h>

#define B_ 64
#define T_ 2048
#define D_ 256
#define H_ 128

typedef float v2f __attribute__((ext_vector_type(2)));

// -------------------------------------------------------------------------
// helpers
// -------------------------------------------------------------------------
__device__ __forceinline__ float hard_sig(float x) {
    return fminf(fmaxf(fmaf(x, 0.2f, 0.5f), 0.0f), 1.0f);
}
__device__ __forceinline__ float fast_tanh(float x) {
    float ax = fabsf(x);
    float e  = __expf(-2.0f * ax);
    float r  = (1.0f - e) * __builtin_amdgcn_rcpf(1.0f + e);
    return copysignf(r, x);
}
__device__ __forceinline__ float softplus_f(float x) {
    float ax = fabsf(x);
    return fmaxf(x, 0.0f) + __logf(1.0f + __expf(-ax));
}

// -------------------------------------------------------------------------
// Projection v2: xx = X@W + b ; xg = X@Wg + bg
// 256 threads: tx = tid&31 -> cols 4*tx.. ; ty = tid>>5 -> rows ty*4..+3
// 32 rows per block (4096 blocks). Double-buffered X AND W register tiles:
// chunk k+1's loads issue while chunk k's FMAs run, hiding the ~200-cycle
// L2 latency that stalled the round-2 version at every 4-k chunk boundary.
// -------------------------------------------------------------------------
__global__ __launch_bounds__(256) void proj_kernel(
    const float* __restrict__ X, const float* __restrict__ W,
    const float* __restrict__ Wg, const float* __restrict__ bias,
    const float* __restrict__ biasg, float* __restrict__ xxw,
    float* __restrict__ xgw, int t0, int Tc)
{
    const int tid = threadIdx.x;
    const int tx  = tid & 31;
    const int ty  = tid >> 5;
    const long rowbase = (long)blockIdx.x * 32;
    const int  b      = (int)(rowbase / Tc);        // Tc % 32 == 0
    const int  ttbase = (int)(rowbase % Tc);
    const float* xbase = X + ((long)b * T_ + t0 + ttbase + ty * 4) * D_;
    const float* wp  = W  + tx * 4;
    const float* wgp = Wg + tx * 4;

    float accx[4][4], accg[4][4];
#pragma unroll
    for (int r = 0; r < 4; ++r)
#pragma unroll
        for (int c = 0; c < 4; ++c) { accx[r][c] = 0.f; accg[r][c] = 0.f; }

    float4 xA[4], xB[4];
    float4 wWA[4], wGA[4], wWB[4], wGB[4];

    // prologue: chunk 0 into A buffers
#pragma unroll
    for (int r = 0; r < 4; ++r) xA[r] = *(const float4*)&xbase[(long)r * D_];
#pragma unroll
    for (int kk = 0; kk < 4; ++kk) {
        wWA[kk] = *(const float4*)&wp [(long)kk * H_];
        wGA[kk] = *(const float4*)&wgp[(long)kk * H_];
    }

#pragma unroll 1
    for (int kc = 0; kc < 64; kc += 2) {
        const int kB  = (kc + 1) * 4;
        const int kA2 = (kc + 2 < 64) ? (kc + 2) * 4 : kB;   // clamp (redundant reload on last iter)

        // ---- prefetch chunk kc+1 into B, compute chunk kc from A ----
#pragma unroll
        for (int r = 0; r < 4; ++r) xB[r] = *(const float4*)&xbase[(long)r * D_ + kB];
#pragma unroll
        for (int kk = 0; kk < 4; ++kk) {
            wWB[kk] = *(const float4*)&wp [(long)(kB + kk) * H_];
            wGB[kk] = *(const float4*)&wgp[(long)(kB + kk) * H_];
        }
#pragma unroll
        for (int r = 0; r < 4; ++r) {
            const float xr[4] = {xA[r].x, xA[r].y, xA[r].z, xA[r].w};
#pragma unroll
            for (int kk = 0; kk < 4; ++kk) {
                accx[r][0] = fmaf(xr[kk], wWA[kk].x, accx[r][0]);
                accx[r][1] = fmaf(xr[kk], wWA[kk].y, accx[r][1]);
                accx[r][2] = fmaf(xr[kk], wWA[kk].z, accx[r][2]);
                accx[r][3] = fmaf(xr[kk], wWA[kk].w, accx[r][3]);
                accg[r][0] = fmaf(xr[kk], wGA[kk].x, accg[r][0]);
                accg[r][1] = fmaf(xr[kk], wGA[kk].y, accg[r][1]);
                accg[r][2] = fmaf(xr[kk], wGA[kk].z, accg[r][2]);
                accg[r][3] = fmaf(xr[kk], wGA[kk].w, accg[r][3]);
            }
        }

        // ---- prefetch chunk kc+2 into A, compute chunk kc+1 from B ----
#pragma unroll
        for (int r = 0; r < 4; ++r) xA[r] = *(const float4*)&xbase[(long)r * D_ + kA2];
#pragma unroll
        for (int kk = 0; kk < 4; ++kk) {
            wWA[kk] = *(const float4*)&wp [(long)(kA2 + kk) * H_];
            wGA[kk] = *(const float4*)&wgp[(long)(kA2 + kk) * H_];
        }
#pragma unroll
        for (int r = 0; r < 4; ++r) {
            const float xr[4] = {xB[r].x, xB[r].y, xB[r].z, xB[r].w};
#pragma unroll
            for (int kk = 0; kk < 4; ++kk) {
                accx[r][0] = fmaf(xr[kk], wWB[kk].x, accx[r][0]);
                accx[r][1] = fmaf(xr[kk], wWB[kk].y, accx[r][1]);
                accx[r][2] = fmaf(xr[kk], wWB[kk].z, accx[r][2]);
                accx[r][3] = fmaf(xr[kk], wWB[kk].w, accx[r][3]);
                accg[r][0] = fmaf(xr[kk], wGB[kk].x, accg[r][0]);
                accg[r][1] = fmaf(xr[kk], wGB[kk].y, accg[r][1]);
                accg[r][2] = fmaf(xr[kk], wGB[kk].z, accg[r][2]);
                accg[r][3] = fmaf(xr[kk], wGB[kk].w, accg[r][3]);
            }
        }
    }

    float4 bj  = *(const float4*)&bias [tx * 4];
    float4 bgj = *(const float4*)&biasg[tx * 4];
#pragma unroll
    for (int r = 0; r < 4; ++r) {
        long row = rowbase + ty * 4 + r;
        float4 ox, og;
        ox.x = accx[r][0] + bj.x;  ox.y = accx[r][1] + bj.y;
        ox.z = accx[r][2] + bj.z;  ox.w = accx[r][3] + bj.w;
        og.x = accg[r][0] + bgj.x; og.y = accg[r][1] + bgj.y;
        og.z = accg[r][2] + bgj.z; og.w = accg[r][3] + bgj.w;
        *(float4*)&xxw[row * H_ + tx * 4] = ox;
        *(float4*)&xgw[row * H_ + tx * 4] = og;
    }
}

// -------------------------------------------------------------------------
// Scan v3: one block per chain, 512 threads = 8 waves.
//   lane (tid&63) = j-pair (2*jp, 2*jp+1); wave q owns i-slice [16q,16q+16)
//   U/Ug pinned in VGPRs (empty-asm defeats rematerialization; round-2's
//   VGPR_Count=48 proved the compiler re-loaded U every step otherwise)
//   matvec: v_readlane h/a into SGPR -> v_fma_f32 with SGPR src (2 fma per
//   readlane pair-element; v_pk_fma_f32 can't take SGPR srcs on gfx950)
//   epilogue distributed: every wave computes the 16 h's it consumes
//   one raw s_barrier/step (lgkmcnt-only drain), double-buffered partials,
//   xx/xg prefetched 2 steps ahead so global loads stay in flight.
// -------------------------------------------------------------------------
__global__ __launch_bounds__(512) void scan_kernel(
    const float* __restrict__ xxw, const float* __restrict__ xgw,
    const float* __restrict__ U, const float* __restrict__ Ug,
    float* __restrict__ hstate, float* __restrict__ hout,
    int t0, int Tc)
{
    const int tid = threadIdx.x;
    const int jp  = tid & 63;        // j-pair index (lane)
    const int q   = tid >> 6;        // wave id 0..7
    const int i0  = q * 16;          // this wave's i-slice
    const int jj  = i0 + (tid & 15); // epilogue h-index (dup x4 across wave)
    const int b   = blockIdx.x;

    __shared__ v2f zb[2][8][64];     // [buf][slice][j-pair] partials, 8KB
    __shared__ v2f gb[2][8][64];     // 8KB

    // U fragments: Up[i] = (U[i0+i][2jp], U[i0+i][2jp+1])
    v2f Up[16], Ugp[16];
#pragma unroll
    for (int i = 0; i < 16; ++i) {
        Up[i]  = *(const v2f*)&U [(long)(i0 + i) * H_ + 2 * jp];
        Ugp[i] = *(const v2f*)&Ug[(long)(i0 + i) * H_ + 2 * jp];
    }
#pragma unroll
    for (int i = 0; i < 16; ++i) {   // pin in VGPRs for the whole kernel
        asm volatile("" : "+v"(Up[i]));
        asm volatile("" : "+v"(Ugp[i]));
    }

    const float* xxb = xxw + (long)b * Tc * H_;
    const float* xgb = xgw + (long)b * Tc * H_;

    float hbank = (t0 == 0) ? 0.0f : hstate[b * H_ + jj];
    float abank = xgb[jj] * hbank;               // a_0 = xg_0 * h_{-1}

    const int t1i = (Tc > 1) ? 1 : 0;
    float xxc = xxb[jj];                         // xx[t]   (epilogue t)
    float xx1 = xxb[(long)t1i * H_ + jj];        // xx[t+1]
    float xg1 = xgb[(long)t1i * H_ + jj];        // xg[t+1] (abank at end of t)

    for (int t = 0; t < Tc; ++t) {
        // ---- prefetch t+2 (lives across the barrier) ----
        int tp = t + 2; if (tp >= Tc) tp = Tc - 1;
        float xx2 = xxb[(long)tp * H_ + jj];
        float xg2 = xgb[(long)tp * H_ + jj];

        // ---- matvec over this wave's 16-i slice: SGPR-broadcast FMA ----
        v2f zpA = {0.f, 0.f}, zpB = {0.f, 0.f};
        v2f gpA = {0.f, 0.f}, gpB = {0.f, 0.f};
        const int hb = __float_as_int(hbank);
        const int ab = __float_as_int(abank);
#pragma unroll
        for (int i = 0; i < 16; i += 2) {
            const float h0 = __int_as_float(__builtin_amdgcn_readlane(hb, i));
            const float a0 = __int_as_float(__builtin_amdgcn_readlane(ab, i));
            const float h1 = __int_as_float(__builtin_amdgcn_readlane(hb, i + 1));
            const float a1 = __int_as_float(__builtin_amdgcn_readlane(ab, i + 1));
            zpA.x = fmaf(h0, Up[i].x,      zpA.x);
            zpA.y = fmaf(h0, Up[i].y,      zpA.y);
            gpA.x = fmaf(a0, Ugp[i].x,     gpA.x);
            gpA.y = fmaf(a0, Ugp[i].y,     gpA.y);
            zpB.x = fmaf(h1, Up[i + 1].x,  zpB.x);
            zpB.y = fmaf(h1, Up[i + 1].y,  zpB.y);
            gpB.x = fmaf(a1, Ugp[i + 1].x, gpB.x);
            gpB.y = fmaf(a1, Ugp[i + 1].y, gpB.y);
        }
        const int buf = t & 1;
        zb[buf][q][jp] = zpA + zpB;
        gb[buf][q][jp] = gpA + gpB;

        // ---- LDS-only drain + raw barrier (prefetches stay in flight) ----
        asm volatile("s_waitcnt lgkmcnt(0)" ::: "memory");
        __builtin_amdgcn_s_barrier();
        asm volatile("" ::: "memory");

        // ---- distributed epilogue: this wave's 16 h's (dup across lanes) --
        const float* zf = (const float*)&zb[buf][0][0];
        const float* gf = (const float*)&gb[buf][0][0];
        float zsum = xxc, gsum = 0.f;
#pragma unroll
        for (int s = 0; s < 8; ++s) {
            zsum += zf[s * 128 + jj];
            gsum += gf[s * 128 + jj];
        }
        float z    = hard_sig(zsum);
        float zg   = fast_tanh(gsum);
        float zo   = softplus_f(hbank * zg);
        float hnew = fmaf(z, zo - hbank, hbank);  // z*zo + (1-z)*h
        hbank = hnew;
        abank = xg1 * hnew;                       // a_{t+1} = xg_{t+1} * h_t
        xxc = xx1; xx1 = xx2; xg1 = xg2;
    }

    if ((tid & 63) < 16) hout[b * H_ + jj] = hbank;
}

// -------------------------------------------------------------------------
// launch
// -------------------------------------------------------------------------
extern "C" void kernel_launch(void* const* d_in, const int* in_sizes, int n_in,
                              void* d_out, int out_size, void* d_ws, size_t ws_size,
                              hipStream_t stream)
{
    const float* X  = (const float*)d_in[0];
    const float* W  = (const float*)d_in[1];
    const float* U  = (const float*)d_in[2];
    const float* bb = (const float*)d_in[3];
    const float* Wg = (const float*)d_in[4];
    const float* bg = (const float*)d_in[5];
    const float* Ug = (const float*)d_in[6];
    float* out = (float*)d_out;

    int Tc = 64;
    const int cands[6] = {2048, 1024, 512, 256, 128, 64};
    for (int ci = 0; ci < 6; ++ci) {
        size_t need = (size_t)2 * B_ * cands[ci] * H_ * sizeof(float)
                    + (size_t)B_ * H_ * sizeof(float);
        if (ws_size >= need) { Tc = cands[ci]; break; }
    }

    float* xxw = (float*)d_ws;
    float* xgw = xxw + (size_t)B_ * Tc * H_;
    float* hst = xgw + (size_t)B_ * Tc * H_;

    for (int t0 = 0; t0 < T_; t0 += Tc) {
        proj_kernel<<<B_ * Tc / 32, 256, 0, stream>>>(X, W, Wg, bb, bg, xxw, xgw, t0, Tc);
        float* ho = (t0 + Tc >= T_) ? out : hst;
        scan_kernel<<<B_, 512, 0, stream>>>(xxw, xgw, U, Ug, hst, ho, t0, Tc);
    }
}

// Round 5
// 1623.771 us; speedup vs baseline: 1.1596x; 1.1013x over previous
//
#include <hip/hip_runtime.h>
#include <math.h>

#define B_ 64
#define T_ 2048
#define D_ 256
#define H_ 128

typedef float v2f __attribute__((ext_vector_type(2)));

// -------------------------------------------------------------------------
// helpers
// -------------------------------------------------------------------------
__device__ __forceinline__ float hard_sig(float x) {
    return fminf(fmaxf(fmaf(x, 0.2f, 0.5f), 0.0f), 1.0f);
}
__device__ __forceinline__ float fast_tanh(float x) {
    float ax = fabsf(x);
    float e  = __expf(-2.0f * ax);
    float r  = (1.0f - e) * __builtin_amdgcn_rcpf(1.0f + e);
    return copysignf(r, x);
}
__device__ __forceinline__ float softplus_f(float x) {
    float ax = fabsf(x);
    return fmaxf(x, 0.0f) + __logf(1.0f + __expf(-ax));
}

// -------------------------------------------------------------------------
// Projection (round-2 version — measured 414 us; round-4 rewrite regressed
// to ~575 us by doubling block count / W refetch, reverted):
// xx = X@W + b ; xg = X@Wg + bg
// 256 threads: tx = tid&31 -> cols 4*tx.. ; ty = tid>>5 -> rows ty*8..+7
// -------------------------------------------------------------------------
__global__ __launch_bounds__(256) void proj_kernel(
    const float* __restrict__ X, const float* __restrict__ W,
    const float* __restrict__ Wg, const float* __restrict__ bias,
    const float* __restrict__ biasg, float* __restrict__ xxw,
    float* __restrict__ xgw, int t0, int Tc)
{
    const int tid = threadIdx.x;
    const int tx  = tid & 31;
    const int ty  = tid >> 5;
    const long rowbase = (long)blockIdx.x * 64;
    const int  b      = (int)(rowbase / Tc);        // Tc % 64 == 0
    const int  ttbase = (int)(rowbase % Tc);
    const float* xbase = X + ((long)b * T_ + t0 + ttbase) * D_;

    float accx[8][4];
    float accg[8][4];
#pragma unroll
    for (int r = 0; r < 8; ++r)
#pragma unroll
        for (int c = 0; c < 4; ++c) { accx[r][c] = 0.f; accg[r][c] = 0.f; }

    for (int k = 0; k < D_; k += 4) {
        float wA[4][4], wG[4][4];
#pragma unroll
        for (int kk = 0; kk < 4; ++kk) {
            float4 tw = *(const float4*)&W [(long)(k + kk) * H_ + tx * 4];
            float4 tg = *(const float4*)&Wg[(long)(k + kk) * H_ + tx * 4];
            wA[kk][0] = tw.x; wA[kk][1] = tw.y; wA[kk][2] = tw.z; wA[kk][3] = tw.w;
            wG[kk][0] = tg.x; wG[kk][1] = tg.y; wG[kk][2] = tg.z; wG[kk][3] = tg.w;
        }
#pragma unroll
        for (int r = 0; r < 8; ++r) {
            float4 xv = *(const float4*)&xbase[(long)(ty * 8 + r) * D_ + k];
            float xr[4] = {xv.x, xv.y, xv.z, xv.w};
#pragma unroll
            for (int c = 0; c < 4; ++c)
#pragma unroll
                for (int kk = 0; kk < 4; ++kk) {
                    accx[r][c] = fmaf(xr[kk], wA[kk][c], accx[r][c]);
                    accg[r][c] = fmaf(xr[kk], wG[kk][c], accg[r][c]);
                }
        }
    }

    float4 bj  = *(const float4*)&bias [tx * 4];
    float4 bgj = *(const float4*)&biasg[tx * 4];
#pragma unroll
    for (int r = 0; r < 8; ++r) {
        long row = rowbase + ty * 8 + r;
        float4 ox, og;
        ox.x = accx[r][0] + bj.x;  ox.y = accx[r][1] + bj.y;
        ox.z = accx[r][2] + bj.z;  ox.w = accx[r][3] + bj.w;
        og.x = accg[r][0] + bgj.x; og.y = accg[r][1] + bgj.y;
        og.z = accg[r][2] + bgj.z; og.w = accg[r][3] + bgj.w;
        *(float4*)&xxw[row * H_ + tx * 4] = ox;
        *(float4*)&xgw[row * H_ + tx * 4] = og;
    }
}

// -------------------------------------------------------------------------
// Scan v4: identical structure to v3, ONE change: __launch_bounds__(512, 2)
// declares 2 waves/EU (= our actual 1 block/CU occupancy), raising the
// compiler's VGPR budget to 256 so Up/Ugp (64 regs) become true arch-VGPR
// residents. Rounds 2/4 both showed VGPR_Count=48: without the min-waves
// spec the allocator capped at ~48 regs and paid ~64 extra VALU accesses
// per wave per step for U (AGPR/remat tax) -> 1423 cyc/step.
// -------------------------------------------------------------------------
__global__ __launch_bounds__(512, 2) void scan_kernel(
    const float* __restrict__ xxw, const float* __restrict__ xgw,
    const float* __restrict__ U, const float* __restrict__ Ug,
    float* __restrict__ hstate, float* __restrict__ hout,
    int t0, int Tc)
{
    const int tid = threadIdx.x;
    const int jp  = tid & 63;        // j-pair index (lane)
    const int q   = tid >> 6;        // wave id 0..7
    const int i0  = q * 16;          // this wave's i-slice
    const int jj  = i0 + (tid & 15); // epilogue h-index (dup x4 across wave)
    const int b   = blockIdx.x;

    __shared__ v2f zb[2][8][64];     // [buf][slice][j-pair] partials, 8KB
    __shared__ v2f gb[2][8][64];     // 8KB

    // U fragments: Up[i] = (U[i0+i][2jp], U[i0+i][2jp+1])
    v2f Up[16], Ugp[16];
#pragma unroll
    for (int i = 0; i < 16; ++i) {
        Up[i]  = *(const v2f*)&U [(long)(i0 + i) * H_ + 2 * jp];
        Ugp[i] = *(const v2f*)&Ug[(long)(i0 + i) * H_ + 2 * jp];
    }
#pragma unroll
    for (int i = 0; i < 16; ++i) {   // pin in VGPRs for the whole kernel
        asm volatile("" : "+v"(Up[i]));
        asm volatile("" : "+v"(Ugp[i]));
    }

    const float* xxb = xxw + (long)b * Tc * H_;
    const float* xgb = xgw + (long)b * Tc * H_;

    float hbank = (t0 == 0) ? 0.0f : hstate[b * H_ + jj];
    float abank = xgb[jj] * hbank;               // a_0 = xg_0 * h_{-1}

    const int t1i = (Tc > 1) ? 1 : 0;
    float xxc = xxb[jj];                         // xx[t]   (epilogue t)
    float xx1 = xxb[(long)t1i * H_ + jj];        // xx[t+1]
    float xg1 = xgb[(long)t1i * H_ + jj];        // xg[t+1] (abank at end of t)

    for (int t = 0; t < Tc; ++t) {
        // ---- prefetch t+2 (lives across the barrier) ----
        int tp = t + 2; if (tp >= Tc) tp = Tc - 1;
        float xx2 = xxb[(long)tp * H_ + jj];
        float xg2 = xgb[(long)tp * H_ + jj];

        // ---- matvec over this wave's 16-i slice: SGPR-broadcast FMA ----
        v2f zpA = {0.f, 0.f}, zpB = {0.f, 0.f};
        v2f gpA = {0.f, 0.f}, gpB = {0.f, 0.f};
        const int hb = __float_as_int(hbank);
        const int ab = __float_as_int(abank);
#pragma unroll
        for (int i = 0; i < 16; i += 2) {
            const float h0 = __int_as_float(__builtin_amdgcn_readlane(hb, i));
            const float a0 = __int_as_float(__builtin_amdgcn_readlane(ab, i));
            const float h1 = __int_as_float(__builtin_amdgcn_readlane(hb, i + 1));
            const float a1 = __int_as_float(__builtin_amdgcn_readlane(ab, i + 1));
            zpA.x = fmaf(h0, Up[i].x,      zpA.x);
            zpA.y = fmaf(h0, Up[i].y,      zpA.y);
            gpA.x = fmaf(a0, Ugp[i].x,     gpA.x);
            gpA.y = fmaf(a0, Ugp[i].y,     gpA.y);
            zpB.x = fmaf(h1, Up[i + 1].x,  zpB.x);
            zpB.y = fmaf(h1, Up[i + 1].y,  zpB.y);
            gpB.x = fmaf(a1, Ugp[i + 1].x, gpB.x);
            gpB.y = fmaf(a1, Ugp[i + 1].y, gpB.y);
        }
        const int buf = t & 1;
        zb[buf][q][jp] = zpA + zpB;
        gb[buf][q][jp] = gpA + gpB;

        // ---- LDS-only drain + raw barrier (prefetches stay in flight) ----
        asm volatile("s_waitcnt lgkmcnt(0)" ::: "memory");
        __builtin_amdgcn_s_barrier();
        asm volatile("" ::: "memory");

        // ---- distributed epilogue: this wave's 16 h's (dup across lanes) --
        const float* zf = (const float*)&zb[buf][0][0];
        const float* gf = (const float*)&gb[buf][0][0];
        float zsum = xxc, gsum = 0.f;
#pragma unroll
        for (int s = 0; s < 8; ++s) {
            zsum += zf[s * 128 + jj];
            gsum += gf[s * 128 + jj];
        }
        float z    = hard_sig(zsum);
        float zg   = fast_tanh(gsum);
        float zo   = softplus_f(hbank * zg);
        float hnew = fmaf(z, zo - hbank, hbank);  // z*zo + (1-z)*h
        hbank = hnew;
        abank = xg1 * hnew;                       // a_{t+1} = xg_{t+1} * h_t
        xxc = xx1; xx1 = xx2; xg1 = xg2;
    }

    if ((tid & 63) < 16) hout[b * H_ + jj] = hbank;
}

// -------------------------------------------------------------------------
// launch
// -------------------------------------------------------------------------
extern "C" void kernel_launch(void* const* d_in, const int* in_sizes, int n_in,
                              void* d_out, int out_size, void* d_ws, size_t ws_size,
                              hipStream_t stream)
{
    const float* X  = (const float*)d_in[0];
    const float* W  = (const float*)d_in[1];
    const float* U  = (const float*)d_in[2];
    const float* bb = (const float*)d_in[3];
    const float* Wg = (const float*)d_in[4];
    const float* bg = (const float*)d_in[5];
    const float* Ug = (const float*)d_in[6];
    float* out = (float*)d_out;

    int Tc = 64;
    const int cands[6] = {2048, 1024, 512, 256, 128, 64};
    for (int ci = 0; ci < 6; ++ci) {
        size_t need = (size_t)2 * B_ * cands[ci] * H_ * sizeof(float)
                    + (size_t)B_ * H_ * sizeof(float);
        if (ws_size >= need) { Tc = cands[ci]; break; }
    }

    float* xxw = (float*)d_ws;
    float* xgw = xxw + (size_t)B_ * Tc * H_;
    float* hst = xgw + (size_t)B_ * Tc * H_;

    for (int t0 = 0; t0 < T_; t0 += Tc) {
        proj_kernel<<<B_ * Tc / 64, 256, 0, stream>>>(X, W, Wg, bb, bg, xxw, xgw, t0, Tc);
        float* ho = (t0 + Tc >= T_) ? out : hst;
        scan_kernel<<<B_, 512, 0, stream>>>(xxw, xgw, U, Ug, hst, ho, t0, Tc);
    }
}